// Round 2
// baseline (311.857 us; speedup 1.0000x reference)
//
#include <hip/hip_runtime.h>

typedef __bf16 bf16;
typedef __bf16 bf16x4 __attribute__((ext_vector_type(4)));
typedef __bf16 bf16x8 __attribute__((ext_vector_type(8)));
typedef float f32x4 __attribute__((ext_vector_type(4)));

#define DIM   2048
#define BQ    128
#define KVL   4096
#define KVT   4224   // KV_LEN + Q_LEN

// Swizzled element offset inside a [ROWS][64]-bf16 LDS tile (128B rows).
// XOR bits 3..5 of element column with row&7 -> conflict-reduced ds_read_b128.
__device__ __forceinline__ int swz(int row, int col) {
  return row * 64 + (col ^ ((row & 7) << 3));
}

// ---- register staging of a ROWSx64 tile (always lands as bf16 in LDS) ----
// Each thread owns CPT=NV4*4 contiguous elements of one row.
template<int ROWS, int NTHR>
struct Stage {
  static constexpr int NV4 = ROWS * 16 / NTHR;   // bf16x4 chunks per thread
  static constexpr int CPT = NV4 * 4;            // elems per thread
  bf16x4 r[NV4];
  int row, c0;
  __device__ __forceinline__ void init(int tid) {
    row = tid / (64 / CPT);
    c0  = (tid % (64 / CPT)) * CPT;
  }
  __device__ __forceinline__ void loadF(const float* __restrict__ src, int ld) {
    const float* p = src + (size_t)row * ld + c0;
    #pragma unroll
    for (int j = 0; j < NV4; ++j) {
      float4 v = *reinterpret_cast<const float4*>(p + 4 * j);
      r[j][0] = (bf16)v.x; r[j][1] = (bf16)v.y;
      r[j][2] = (bf16)v.z; r[j][3] = (bf16)v.w;
    }
  }
  __device__ __forceinline__ void loadB(const bf16* __restrict__ src, int ld) {
    const bf16* p = src + (size_t)row * ld + c0;
    #pragma unroll
    for (int j = 0; j < NV4; j += 2) {
      bf16x8 v = *reinterpret_cast<const bf16x8*>(p + 4 * j);
      r[j][0] = v[0]; r[j][1] = v[1]; r[j][2] = v[2]; r[j][3] = v[3];
      r[j+1][0] = v[4]; r[j+1][1] = v[5]; r[j+1][2] = v[6]; r[j+1][3] = v[7];
    }
  }
  __device__ __forceinline__ void store(bf16* dst) {
    #pragma unroll
    for (int j = 0; j < NV4; ++j)
      *reinterpret_cast<bf16x4*>(dst + swz(row, c0 + 4 * j)) = r[j];
  }
};

// ---- transpose staging: V[64k][DIM] slice -> VT[64d][64k] bf16 LDS ----
struct StageVT {
  bf16x4 r[2];
  int vn, vk0;
  __device__ __forceinline__ void init(int tid) { vn = tid & 63; vk0 = (tid >> 6) * 8; }
  __device__ __forceinline__ void loadF(const float* __restrict__ src) {
    const float* p = src + (size_t)vk0 * DIM + vn;
    #pragma unroll
    for (int j = 0; j < 2; ++j)
      #pragma unroll
      for (int i = 0; i < 4; ++i) r[j][i] = (bf16)p[(size_t)(4 * j + i) * DIM];
  }
  __device__ __forceinline__ void loadB(const bf16* __restrict__ src) {
    const bf16* p = src + (size_t)vk0 * DIM + vn;
    #pragma unroll
    for (int j = 0; j < 2; ++j)
      #pragma unroll
      for (int i = 0; i < 4; ++i) r[j][i] = p[(size_t)(4 * j + i) * DIM];
  }
  __device__ __forceinline__ void store(bf16* dst) {
    *reinterpret_cast<bf16x4*>(dst + swz(vn, vk0))     = r[0];
    *reinterpret_cast<bf16x4*>(dst + swz(vn, vk0 + 4)) = r[1];
  }
};

// ---- wave tile: MF x NF fragments of 16x16, K-depth 64 (2 mfma k-steps) ----
template<int MF, int NF>
__device__ __forceinline__ void mma_tile(const bf16* As, const bf16* Bs,
                                         f32x4 (&acc)[MF][NF], int l, int wm, int wn) {
  const int ar = l & 15;
  const int ak = (l >> 4) * 8;
  bf16x8 a[MF][2], b[NF][2];
  #pragma unroll
  for (int mi = 0; mi < MF; ++mi)
    #pragma unroll
    for (int kk = 0; kk < 2; ++kk)
      a[mi][kk] = *reinterpret_cast<const bf16x8*>(As + swz(wm + mi * 16 + ar, kk * 32 + ak));
  #pragma unroll
  for (int ni = 0; ni < NF; ++ni)
    #pragma unroll
    for (int kk = 0; kk < 2; ++kk)
      b[ni][kk] = *reinterpret_cast<const bf16x8*>(Bs + swz(wn + ni * 16 + ar, kk * 32 + ak));
  #pragma unroll
  for (int kk = 0; kk < 2; ++kk)
    #pragma unroll
    for (int mi = 0; mi < MF; ++mi)
      #pragma unroll
      for (int ni = 0; ni < NF; ++ni)
        acc[mi][ni] = __builtin_amdgcn_mfma_f32_16x16x32_bf16(
            a[mi][kk], b[ni][kk], acc[mi][ni], 0, 0, 0);
}

// ============ Kernel A: q/k/v projections (x @ W^T), 128x128 tiles ============
// grid (48, 8): 48 = 3 weights * 16 n-tiles of 128; 8 m-tiles of 128.
__global__ __launch_bounds__(512) void k_qkv(const float* __restrict__ x,
    const float* __restrict__ wq, const float* __restrict__ wk,
    const float* __restrict__ wv,
    bf16* __restrict__ qb, bf16* __restrict__ kb, bf16* __restrict__ vb) {
  __shared__ bf16 As[2][128 * 64];
  __shared__ bf16 Bs[2][128 * 64];
  const int nt = blockIdx.x;
  const int w  = nt >> 4;
  const int nloc = (nt & 15) * 128;
  const float* __restrict__ W = (w == 0) ? wq : (w == 1) ? wk : wv;
  bf16* __restrict__ O = (w == 0) ? qb : (w == 1) ? kb : vb;
  const int m0 = blockIdx.y * 128;
  const int tid = threadIdx.x, l = tid & 63, wid = tid >> 6;
  const int wm = (wid >> 2) * 64, wn = (wid & 3) * 32;
  Stage<128, 512> sa, sb;
  sa.init(tid); sb.init(tid);
  const float* Ap = x + (size_t)m0 * DIM;
  const float* Bp = W + (size_t)nloc * DIM;
  f32x4 acc[4][2] = {};
  sa.loadF(Ap, DIM); sb.loadF(Bp, DIM);
  sa.store(As[0]); sb.store(Bs[0]);
  __syncthreads();
  int cur = 0;
  for (int kt = 0; kt < DIM / 64; ++kt) {
    if (kt + 1 < DIM / 64) { sa.loadF(Ap + (kt + 1) * 64, DIM); sb.loadF(Bp + (kt + 1) * 64, DIM); }
    mma_tile<4, 2>(As[cur], Bs[cur], acc, l, wm, wn);
    if (kt + 1 < DIM / 64) { sa.store(As[cur ^ 1]); sb.store(Bs[cur ^ 1]); }
    __syncthreads();
    cur ^= 1;
  }
  const int rr = (l >> 4) * 4, cc = l & 15;
  #pragma unroll
  for (int mi = 0; mi < 4; ++mi)
    #pragma unroll
    for (int ni = 0; ni < 2; ++ni)
      #pragma unroll
      for (int r = 0; r < 4; ++r) {
        int row = m0 + wm + mi * 16 + rr + r;
        int col = nloc + wn + ni * 16 + cc;
        O[(size_t)row * DIM + col] = (bf16)acc[mi][ni][r];
      }
}

// ============ Kernel B: scores = scale * q @ k^T, 128x128 tiles ============
// grid (33, 8): nt 0..31 -> k_cache rows (fp32), nt==32 -> k_new (bf16).
__global__ __launch_bounds__(512) void k_scores(const bf16* __restrict__ qb,
    const bf16* __restrict__ kb, const float* __restrict__ kcache,
    float* __restrict__ scores) {
  __shared__ bf16 As[2][128 * 64];
  __shared__ bf16 Bs[2][128 * 64];
  const int nt = blockIdx.x;
  const int b  = blockIdx.y;
  const int tid = threadIdx.x, l = tid & 63, wid = tid >> 6;
  const int wm = (wid >> 2) * 64, wn = (wid & 3) * 32;
  const bf16* Q = qb + (size_t)b * BQ * DIM;
  const bool useCache = (nt < 32);
  const float* Bf = kcache + ((size_t)b * KVL + nt * 128) * DIM;
  const bf16*  Bb = kb + (size_t)b * BQ * DIM;
  Stage<128, 512> sa, sb;
  sa.init(tid); sb.init(tid);
  f32x4 acc[4][2] = {};
  sa.loadB(Q, DIM);
  if (useCache) sb.loadF(Bf, DIM); else sb.loadB(Bb, DIM);
  sa.store(As[0]); sb.store(Bs[0]);
  __syncthreads();
  int cur = 0;
  for (int kt = 0; kt < DIM / 64; ++kt) {
    if (kt + 1 < DIM / 64) {
      sa.loadB(Q + (kt + 1) * 64, DIM);
      if (useCache) sb.loadF(Bf + (kt + 1) * 64, DIM); else sb.loadB(Bb + (kt + 1) * 64, DIM);
    }
    mma_tile<4, 2>(As[cur], Bs[cur], acc, l, wm, wn);
    if (kt + 1 < DIM / 64) { sa.store(As[cur ^ 1]); sb.store(Bs[cur ^ 1]); }
    __syncthreads();
    cur ^= 1;
  }
  const float scale = 0.022097086912079608f;  // 1/sqrt(2048)
  const int rr = (l >> 4) * 4, cc = l & 15;
  #pragma unroll
  for (int mi = 0; mi < 4; ++mi)
    #pragma unroll
    for (int ni = 0; ni < 2; ++ni)
      #pragma unroll
      for (int r = 0; r < 4; ++r) {
        int row = wm + mi * 16 + rr + r;
        int col = nt * 128 + wn + ni * 16 + cc;
        scores[((size_t)b * BQ + row) * KVT + col] = acc[mi][ni][r] * scale;
      }
}

// ================= Kernel C: row softmax -> bf16 attn =================
__global__ __launch_bounds__(256) void k_softmax(const float* __restrict__ scores,
                                                 bf16* __restrict__ attn) {
  __shared__ float s[KVT];
  __shared__ float red[8];
  const int row = blockIdx.x;           // 0..1023
  const int tid = threadIdx.x;
  const size_t base = (size_t)row * KVT;
  float lm = -1e30f;
  for (int i = tid; i < KVT; i += 256) {
    float v = scores[base + i];
    s[i] = v;
    lm = fmaxf(lm, v);
  }
  #pragma unroll
  for (int off = 32; off >= 1; off >>= 1) lm = fmaxf(lm, __shfl_xor(lm, off, 64));
  if ((tid & 63) == 0) red[tid >> 6] = lm;
  __syncthreads();
  const float m = fmaxf(fmaxf(red[0], red[1]), fmaxf(red[2], red[3]));
  float ls = 0.f;
  for (int i = tid; i < KVT; i += 256) {
    float e = __expf(s[i] - m);
    s[i] = e;
    ls += e;
  }
  #pragma unroll
  for (int off = 32; off >= 1; off >>= 1) ls += __shfl_xor(ls, off, 64);
  if ((tid & 63) == 0) red[4 + (tid >> 6)] = ls;
  __syncthreads();
  const float inv = 1.f / (red[4] + red[5] + red[6] + red[7]);
  for (int i = tid; i < KVT; i += 256) attn[base + i] = (bf16)(s[i] * inv);
}

// ============ Kernel D: out = attn @ V, 128x64 tiles, K=4224 ============
// grid (32, 8). kt<64 -> v_cache (fp32), else v_new (bf16). V transpose-staged.
__global__ __launch_bounds__(512) void k_pv(const bf16* __restrict__ attn,
    const float* __restrict__ vcache, const bf16* __restrict__ vb,
    bf16* __restrict__ ob) {
  __shared__ bf16 As[2][128 * 64];
  __shared__ bf16 VT[2][64 * 64];
  const int n0 = blockIdx.x * 64;
  const int b  = blockIdx.y;
  const int tid = threadIdx.x, l = tid & 63, wid = tid >> 6;
  const int wm = (wid >> 1) * 32, wn = (wid & 1) * 32;   // 8 waves: 4m x 2n
  const bf16* Ap = attn + (size_t)b * BQ * KVT;
  Stage<128, 512> sa; sa.init(tid);
  StageVT sv; sv.init(tid);
  f32x4 acc[2][2] = {};
  sa.loadB(Ap, KVT);
  sv.loadF(vcache + (size_t)b * KVL * DIM + n0);
  sa.store(As[0]); sv.store(VT[0]);
  __syncthreads();
  int cur = 0;
  for (int kt = 0; kt < KVT / 64; ++kt) {
    if (kt + 1 < KVT / 64) {
      const int k1 = (kt + 1) * 64;
      sa.loadB(Ap + k1, KVT);
      if (kt + 1 < 64) sv.loadF(vcache + ((size_t)b * KVL + k1) * DIM + n0);
      else             sv.loadB(vb + ((size_t)b * BQ + (k1 - KVL)) * DIM + n0);
    }
    mma_tile<2, 2>(As[cur], VT[cur], acc, l, wm, wn);
    if (kt + 1 < KVT / 64) { sa.store(As[cur ^ 1]); sv.store(VT[cur ^ 1]); }
    __syncthreads();
    cur ^= 1;
  }
  const int rr = (l >> 4) * 4, cc = l & 15;
  #pragma unroll
  for (int mi = 0; mi < 2; ++mi)
    #pragma unroll
    for (int ni = 0; ni < 2; ++ni)
      #pragma unroll
      for (int r = 0; r < 4; ++r) {
        int row = wm + mi * 16 + rr + r;
        int col = n0 + wn + ni * 16 + cc;
        ob[((size_t)b * BQ + row) * DIM + col] = (bf16)acc[mi][ni][r];
      }
}

// ============ Kernel E: final = out @ wo^T (fp32), 128x64 tiles ============
// grid (32, 8).
__global__ __launch_bounds__(512) void k_oproj(const bf16* __restrict__ ob,
    const float* __restrict__ wo, float* __restrict__ out) {
  __shared__ bf16 As[2][128 * 64];
  __shared__ bf16 Bs[2][64 * 64];
  const int n0 = blockIdx.x * 64;
  const int m0 = blockIdx.y * 128;
  const int tid = threadIdx.x, l = tid & 63, wid = tid >> 6;
  const int wm = (wid >> 1) * 32, wn = (wid & 1) * 32;   // 8 waves: 4m x 2n
  Stage<128, 512> sa; sa.init(tid);
  Stage<64, 512>  sb; sb.init(tid);
  const bf16*  Apb = ob + (size_t)m0 * DIM;
  const float* Bpf = wo + (size_t)n0 * DIM;
  f32x4 acc[2][2] = {};
  sa.loadB(Apb, DIM); sb.loadF(Bpf, DIM);
  sa.store(As[0]); sb.store(Bs[0]);
  __syncthreads();
  int cur = 0;
  for (int kt = 0; kt < DIM / 64; ++kt) {
    if (kt + 1 < DIM / 64) { sa.loadB(Apb + (kt + 1) * 64, DIM); sb.loadF(Bpf + (kt + 1) * 64, DIM); }
    mma_tile<2, 2>(As[cur], Bs[cur], acc, l, wm, wn);
    if (kt + 1 < DIM / 64) { sa.store(As[cur ^ 1]); sb.store(Bs[cur ^ 1]); }
    __syncthreads();
    cur ^= 1;
  }
  const int rr = (l >> 4) * 4, cc = l & 15;
  #pragma unroll
  for (int mi = 0; mi < 2; ++mi)
    #pragma unroll
    for (int ni = 0; ni < 2; ++ni)
      #pragma unroll
      for (int r = 0; r < 4; ++r) {
        int row = m0 + wm + mi * 16 + rr + r;
        int col = n0 + wn + ni * 16 + cc;
        out[(size_t)row * DIM + col] = acc[mi][ni][r];
      }
}

extern "C" void kernel_launch(void* const* d_in, const int* in_sizes, int n_in,
                              void* d_out, int out_size, void* d_ws, size_t ws_size,
                              hipStream_t stream) {
  const float* x      = (const float*)d_in[0];
  // d_in[1] = mask (unused by the reference forward)
  const float* kcache = (const float*)d_in[2];
  const float* vcache = (const float*)d_in[3];
  const float* wq     = (const float*)d_in[4];
  const float* wk     = (const float*)d_in[5];
  const float* wv     = (const float*)d_in[6];
  const float* wo     = (const float*)d_in[7];
  float* out = (float*)d_out;

  char* ws = (char*)d_ws;
  bf16*  qb     = (bf16*)(ws + 0);                    //  4 MB  [1024][2048]
  bf16*  kb     = (bf16*)(ws + 4194304);              //  4 MB
  bf16*  vb     = (bf16*)(ws + 8388608);              //  4 MB
  float* scores = (float*)(ws + 12582912);            // 17.3 MB [1024][4224]
  bf16*  attnb  = (bf16*)(ws + 29884416);             //  8.65 MB
  bf16*  obuf   = (bf16*)(ws + 38535168);             //  4 MB

  k_qkv<<<dim3(48, 8), 512, 0, stream>>>(x, wq, wk, wv, qb, kb, vb);
  k_scores<<<dim3(33, 8), 512, 0, stream>>>(qb, kb, kcache, scores);
  k_softmax<<<dim3(1024), 256, 0, stream>>>(scores, attnb);
  k_pv<<<dim3(32, 8), 512, 0, stream>>>(attnb, vcache, vb, obuf);
  k_oproj<<<dim3(32, 8), 512, 0, stream>>>(obuf, wo, out);
}